// Round 1
// baseline (266.350 us; speedup 1.0000x reference)
//
#include <hip/hip_runtime.h>

// ---------------------------------------------------------------------------
// Attention block, faithful to reference quirks:
//  - raw reshape head split: per (b,h) Q/K/V are contiguous [2048,64] slabs
//  - softmax over QUERY axis: attn[q,k] = exp(s[q,k]) / sum_q exp(s[q,k])
// Pipeline: f32->bf16 convert | QKV GEMM (Q pre-scaled 1/8) | V transpose |
//           column-sum (LZ=-log sum_q exp(s)) | fused S/exp/PV | out GEMM+bias
// ---------------------------------------------------------------------------

typedef short s16v8 __attribute__((ext_vector_type(8)));
typedef float f32x4 __attribute__((ext_vector_type(4)));

#define BATCH_STRIDE 1048576   // T*D = 2048*512
#define HEAD_STRIDE  131072    // T*hd = 2048*64

__device__ __forceinline__ unsigned short f2bf(float f) {
  unsigned int u = __builtin_bit_cast(unsigned int, f);
  u = (u + 0x7FFFu + ((u >> 16) & 1u)) >> 16;   // round-to-nearest-even
  return (unsigned short)u;
}

// swizzled LDS tile: 16B chunk at slot = row*8 + (chunk ^ (row&7))
__device__ __forceinline__ s16v8 ldsfrag(const unsigned short* base, int row, int ch) {
  return *(const s16v8*)(base + (((row) << 3) + ((ch) ^ ((row) & 7))) * 8);
}

__device__ __forceinline__ f32x4 mfma16(s16v8 a, s16v8 b, f32x4 c) {
  return __builtin_amdgcn_mfma_f32_16x16x32_bf16(a, b, c, 0, 0, 0);
}

// ---------------------------------------------------------------------------
// Kernel: f32 -> bf16 for X and the 4 weight matrices
// grid: 5120 x 256, each thread one float4
// ---------------------------------------------------------------------------
__global__ __launch_bounds__(256) void k_convert(
    const float* __restrict__ X, const float* __restrict__ Wq,
    const float* __restrict__ Wk, const float* __restrict__ Wv,
    const float* __restrict__ Wo, unsigned short* __restrict__ Xb,
    unsigned short* __restrict__ Wb) {
  int id = blockIdx.x * 256 + threadIdx.x;  // float4 index
  const float* src;
  unsigned short* dst;
  int idx;
  if (id < 1048576) {          // X: 4,194,304 floats
    src = X; dst = Xb; idx = id;
  } else {
    int t = id - 1048576;
    int w = t >> 16;           // 65536 float4 per 512x512 weight
    idx = t & 65535;
    src = (w == 0) ? Wq : (w == 1) ? Wk : (w == 2) ? Wv : Wo;
    dst = Wb + w * 262144;
  }
  float4 v = ((const float4*)src)[idx];
  ushort4 o;
  o.x = f2bf(v.x); o.y = f2bf(v.y); o.z = f2bf(v.z); o.w = f2bf(v.w);
  ((ushort4*)dst)[idx] = o;
}

// ---------------------------------------------------------------------------
// GEMM body: D[i,j] = alpha * sum_d A[i,d]*W[j,d]  (+bias, f32 out for final)
// BM=128 BN=64 BK=64, 4 waves in 2x2, wave tile 64x32
// ---------------------------------------------------------------------------
__device__ __forceinline__ void gemm_body(
    const unsigned short* __restrict__ A, const unsigned short* __restrict__ W,
    unsigned short* __restrict__ Dbf, float* __restrict__ Dfp,
    const float* __restrict__ bias, float alpha, int m0, int n0) {
  __shared__ __align__(16) unsigned short At[128 * 64];
  __shared__ __align__(16) unsigned short Bt[64 * 64];
  const int tid = threadIdx.x;
  const int lane = tid & 63, wid = tid >> 6;
  const int l16 = lane & 15, lg = lane >> 4;
  const int wm = (wid >> 1) * 64, wn = (wid & 1) * 32;

  const f32x4 z4 = {0.f, 0.f, 0.f, 0.f};
  f32x4 acc[4][2];
#pragma unroll
  for (int i = 0; i < 4; i++)
#pragma unroll
    for (int j = 0; j < 2; j++) acc[i][j] = z4;

#pragma unroll 1
  for (int k0 = 0; k0 < 512; k0 += 64) {
    uint4 ar[4], br[2];
#pragma unroll
    for (int c = 0; c < 4; c++) {
      int cid = tid * 4 + c, row = cid >> 3, ch = cid & 7;
      ar[c] = *(const uint4*)(A + (size_t)(m0 + row) * 512 + k0 + ch * 8);
    }
#pragma unroll
    for (int c = 0; c < 2; c++) {
      int cid = tid * 2 + c, row = cid >> 3, ch = cid & 7;
      br[c] = *(const uint4*)(W + (size_t)(n0 + row) * 512 + k0 + ch * 8);
    }
    __syncthreads();
#pragma unroll
    for (int c = 0; c < 4; c++) {
      int cid = tid * 4 + c, row = cid >> 3, ch = cid & 7;
      *(uint4*)(At + ((row << 3) + (ch ^ (row & 7))) * 8) = ar[c];
    }
#pragma unroll
    for (int c = 0; c < 2; c++) {
      int cid = tid * 2 + c, row = cid >> 3, ch = cid & 7;
      *(uint4*)(Bt + ((row << 3) + (ch ^ (row & 7))) * 8) = br[c];
    }
    __syncthreads();
    s16v8 af[4][2], bfr[2][2];
#pragma unroll
    for (int ms = 0; ms < 4; ms++)
#pragma unroll
      for (int ks = 0; ks < 2; ks++)
        af[ms][ks] = ldsfrag(At, wm + ms * 16 + l16, ks * 4 + lg);
#pragma unroll
    for (int ns = 0; ns < 2; ns++)
#pragma unroll
      for (int ks = 0; ks < 2; ks++)
        bfr[ns][ks] = ldsfrag(Bt, wn + ns * 16 + l16, ks * 4 + lg);
#pragma unroll
    for (int ms = 0; ms < 4; ms++)
#pragma unroll
      for (int ns = 0; ns < 2; ns++)
#pragma unroll
        for (int ks = 0; ks < 2; ks++)
          acc[ms][ns] = mfma16(af[ms][ks], bfr[ns][ks], acc[ms][ns]);
  }
#pragma unroll
  for (int ms = 0; ms < 4; ms++)
#pragma unroll
    for (int ns = 0; ns < 2; ns++) {
      int gcol = n0 + wn + ns * 16 + l16;
#pragma unroll
      for (int r = 0; r < 4; r++) {
        int grow = m0 + wm + ms * 16 + lg * 4 + r;
        float v = acc[ms][ns][r] * alpha;
        if (Dbf) Dbf[(size_t)grow * 512 + gcol] = f2bf(v);
        else Dfp[(size_t)grow * 512 + gcol] = v + bias[gcol];
      }
    }
}

__global__ __launch_bounds__(256) void k_gemm_qkv(
    const unsigned short* __restrict__ Xb, const unsigned short* __restrict__ Wb,
    unsigned short* __restrict__ QKV) {
  int z = blockIdx.z;
  gemm_body(Xb, Wb + z * 262144, QKV + (size_t)z * 4194304, nullptr, nullptr,
            z == 0 ? 0.125f : 1.0f, blockIdx.x * 128, blockIdx.y * 64);
}

__global__ __launch_bounds__(256) void k_gemm_out(
    const unsigned short* __restrict__ AO, const unsigned short* __restrict__ Wob,
    float* __restrict__ out, const float* __restrict__ bias) {
  gemm_body(AO, Wob, nullptr, out, bias, 1.0f, blockIdx.x * 128, blockIdx.y * 64);
}

// ---------------------------------------------------------------------------
// V transpose per (b,h): Vst[d][k] = V[k][d]   (so PV B-frags read contiguous)
// grid: (32 ktiles, 32 bh) x 256
// ---------------------------------------------------------------------------
__global__ __launch_bounds__(256) void k_vtrans(
    const unsigned short* __restrict__ Vb, unsigned short* __restrict__ Vst) {
  const int kt = blockIdx.x, bh = blockIdx.y;
  const int b = bh >> 3, h = bh & 7;
  const size_t base = (size_t)b * BATCH_STRIDE + h * HEAD_STRIDE;
  const unsigned short* src = Vb + base + kt * 4096;  // [64 k][64 d] contiguous
  unsigned short* dst = Vst + base + kt * 64;         // Vst [64 d][2048 k]
  __shared__ __align__(16) unsigned short L[64][72];
  const int tid = threadIdx.x;
#pragma unroll
  for (int c = 0; c < 2; c++) {
    int cid = tid * 2 + c, row = cid >> 3, ch = cid & 7;
    *(uint4*)(&L[row][ch * 8]) = *(const uint4*)(src + row * 64 + ch * 8);
  }
  __syncthreads();
#pragma unroll
  for (int c = 0; c < 2; c++) {
    int cid = tid * 2 + c, d = cid >> 3, ch = cid & 7;
    unsigned short tmp[8];
#pragma unroll
    for (int j = 0; j < 8; j++) tmp[j] = L[ch * 8 + j][d];
    *(uint4*)(dst + (size_t)d * 2048 + ch * 8) = *(const uint4*)tmp;
  }
}

// ---------------------------------------------------------------------------
// Column softmax denominator: LZ[bh,k] = -log( sum_q exp(s[q,k]) )
// wg = (kb: 128 k cols, bh); wave owns 32 k cols; loop q in 64-tiles
// ---------------------------------------------------------------------------
__global__ __launch_bounds__(256) void k_colsum(
    const unsigned short* __restrict__ Qb, const unsigned short* __restrict__ Kb,
    float* __restrict__ LZ) {
  const int kb = blockIdx.x, bh = blockIdx.y;
  const int b = bh >> 3, h = bh & 7;
  const size_t base = (size_t)b * BATCH_STRIDE + h * HEAD_STRIDE;
  const unsigned short* Qg = Qb + base;
  const unsigned short* Kg = Kb + base + kb * 8192;  // 128 rows * 64
  __shared__ __align__(16) unsigned short Kt[128 * 64];
  __shared__ __align__(16) unsigned short Qt[64 * 64];
  const int tid = threadIdx.x, lane = tid & 63, wid = tid >> 6;
  const int l16 = lane & 15, lg = lane >> 4;

#pragma unroll
  for (int c = 0; c < 4; c++) {
    int cid = tid * 4 + c, row = cid >> 3, ch = cid & 7;
    uint4 v = *(const uint4*)(Kg + row * 64 + ch * 8);
    *(uint4*)(Kt + ((row << 3) + (ch ^ (row & 7))) * 8) = v;
  }
  __syncthreads();
  s16v8 kf[2][2];
#pragma unroll
  for (int ns = 0; ns < 2; ns++)
#pragma unroll
    for (int ks = 0; ks < 2; ks++)
      kf[ns][ks] = ldsfrag(Kt, wid * 32 + ns * 16 + l16, ks * 4 + lg);

  const f32x4 z4 = {0.f, 0.f, 0.f, 0.f};
  float zsum0 = 0.f, zsum1 = 0.f;
#pragma unroll 1
  for (int q0 = 0; q0 < 2048; q0 += 64) {
    uint4 qr[2];
#pragma unroll
    for (int c = 0; c < 2; c++) {
      int cid = tid * 2 + c, row = cid >> 3, ch = cid & 7;
      qr[c] = *(const uint4*)(Qg + (size_t)(q0 + row) * 64 + ch * 8);
    }
    __syncthreads();
#pragma unroll
    for (int c = 0; c < 2; c++) {
      int cid = tid * 2 + c, row = cid >> 3, ch = cid & 7;
      *(uint4*)(Qt + ((row << 3) + (ch ^ (row & 7))) * 8) = qr[c];
    }
    __syncthreads();
#pragma unroll
    for (int ms = 0; ms < 4; ms++) {
      s16v8 a0 = ldsfrag(Qt, ms * 16 + l16, lg);
      s16v8 a1 = ldsfrag(Qt, ms * 16 + l16, 4 + lg);
      f32x4 s0 = z4, s1 = z4;
      s0 = mfma16(a0, kf[0][0], s0);
      s0 = mfma16(a1, kf[0][1], s0);
      s1 = mfma16(a0, kf[1][0], s1);
      s1 = mfma16(a1, kf[1][1], s1);
#pragma unroll
      for (int r = 0; r < 4; r++) {
        zsum0 += __expf(s0[r]);
        zsum1 += __expf(s1[r]);
      }
    }
  }
  zsum0 += __shfl_xor(zsum0, 16); zsum0 += __shfl_xor(zsum0, 32);
  zsum1 += __shfl_xor(zsum1, 16); zsum1 += __shfl_xor(zsum1, 32);
  if (lane < 16) {
    LZ[(size_t)bh * 2048 + kb * 128 + wid * 32 + lane]      = -__logf(zsum0);
    LZ[(size_t)bh * 2048 + kb * 128 + wid * 32 + 16 + lane] = -__logf(zsum1);
  }
}

// ---------------------------------------------------------------------------
// Fused attention: AO[q,d] = sum_k exp(s[q,k]+LZ[k]) * V[k,d]
// wg = (qb: 128 q rows, bh); wave owns 32 q rows; loop k in 64-tiles
// ---------------------------------------------------------------------------
__global__ __launch_bounds__(256) void k_attn(
    const unsigned short* __restrict__ Qb, const unsigned short* __restrict__ Kb,
    const unsigned short* __restrict__ Vst, const float* __restrict__ LZ,
    unsigned short* __restrict__ AO) {
  const int qb = blockIdx.x, bh = blockIdx.y;
  const int b = bh >> 3, h = bh & 7;
  const size_t base = (size_t)b * BATCH_STRIDE + h * HEAD_STRIDE;
  const unsigned short* Qg = Qb + base + qb * 8192;
  const unsigned short* Kg = Kb + base;
  const unsigned short* Vg = Vst + base;
  const float* lzg = LZ + (size_t)bh * 2048;
  unsigned short* aog = AO + base + qb * 8192;

  __shared__ __align__(16) unsigned short Qt[128 * 64];
  __shared__ __align__(16) unsigned short Kt[64 * 64];
  __shared__ __align__(16) unsigned short Vt[64 * 64];
  __shared__ __align__(16) float Pw[4][32 * 36];
  __shared__ float lzs[64];

  const int tid = threadIdx.x, lane = tid & 63, wid = tid >> 6;
  const int l16 = lane & 15, lg = lane >> 4;

#pragma unroll
  for (int c = 0; c < 4; c++) {
    int cid = tid * 4 + c, row = cid >> 3, ch = cid & 7;
    uint4 v = *(const uint4*)(Qg + row * 64 + ch * 8);
    *(uint4*)(Qt + ((row << 3) + (ch ^ (row & 7))) * 8) = v;
  }
  __syncthreads();
  s16v8 qa[2][2];
#pragma unroll
  for (int ms = 0; ms < 2; ms++)
#pragma unroll
    for (int ks = 0; ks < 2; ks++)
      qa[ms][ks] = ldsfrag(Qt, wid * 32 + ms * 16 + l16, ks * 4 + lg);

  const f32x4 z4 = {0.f, 0.f, 0.f, 0.f};
  f32x4 oacc[2][4];
#pragma unroll
  for (int ms = 0; ms < 2; ms++)
#pragma unroll
    for (int dt = 0; dt < 4; dt++) oacc[ms][dt] = z4;

#pragma unroll 1
  for (int k0 = 0; k0 < 2048; k0 += 64) {
    uint4 kr[2], vr[2];
    float lzv = 0.f;
#pragma unroll
    for (int c = 0; c < 2; c++) {
      int cid = tid * 2 + c, row = cid >> 3, ch = cid & 7;
      kr[c] = *(const uint4*)(Kg + (size_t)(k0 + row) * 64 + ch * 8);
      vr[c] = *(const uint4*)(Vg + (size_t)row * 2048 + k0 + ch * 8);
    }
    if (tid < 64) lzv = lzg[k0 + tid];
    __syncthreads();
#pragma unroll
    for (int c = 0; c < 2; c++) {
      int cid = tid * 2 + c, row = cid >> 3, ch = cid & 7;
      *(uint4*)(Kt + ((row << 3) + (ch ^ (row & 7))) * 8) = kr[c];
      *(uint4*)(Vt + ((row << 3) + (ch ^ (row & 7))) * 8) = vr[c];
    }
    if (tid < 64) lzs[tid] = lzv;
    __syncthreads();

    f32x4 sacc[2][4];
#pragma unroll
    for (int ms = 0; ms < 2; ms++)
#pragma unroll
      for (int kc = 0; kc < 4; kc++) sacc[ms][kc] = z4;
#pragma unroll
    for (int kc = 0; kc < 4; kc++)
#pragma unroll
      for (int ks = 0; ks < 2; ks++) {
        s16v8 kfr = ldsfrag(Kt, kc * 16 + l16, ks * 4 + lg);
        sacc[0][kc] = mfma16(qa[0][ks], kfr, sacc[0][kc]);
        sacc[1][kc] = mfma16(qa[1][ks], kfr, sacc[1][kc]);
      }

#pragma unroll
    for (int half = 0; half < 2; half++) {
#pragma unroll
      for (int kc2 = 0; kc2 < 2; kc2++) {
        int kc = half * 2 + kc2;
        float lz = lzs[kc * 16 + l16];
#pragma unroll
        for (int ms = 0; ms < 2; ms++)
#pragma unroll
          for (int r = 0; r < 4; r++) {
            float p = __expf(sacc[ms][kc][r] + lz);
            Pw[wid][(ms * 16 + lg * 4 + r) * 36 + kc2 * 16 + l16] = p;
          }
      }
      s16v8 pa[2];
#pragma unroll
      for (int ms = 0; ms < 2; ms++) {
        const float* p = &Pw[wid][(ms * 16 + l16) * 36 + lg * 8];
        s16v8 t;
#pragma unroll
        for (int j = 0; j < 8; j++) t[j] = (short)f2bf(p[j]);
        pa[ms] = t;
      }
#pragma unroll
      for (int dt = 0; dt < 4; dt++) {
        s16v8 vb = ldsfrag(Vt, dt * 16 + l16, half * 4 + lg);
        oacc[0][dt] = mfma16(pa[0], vb, oacc[0][dt]);
        oacc[1][dt] = mfma16(pa[1], vb, oacc[1][dt]);
      }
    }
  }
#pragma unroll
  for (int ms = 0; ms < 2; ms++)
#pragma unroll
    for (int dt = 0; dt < 4; dt++)
#pragma unroll
      for (int r = 0; r < 4; r++) {
        int row = wid * 32 + ms * 16 + lg * 4 + r;
        aog[row * 64 + dt * 16 + l16] = f2bf(oacc[ms][dt][r]);
      }
}

// ---------------------------------------------------------------------------
extern "C" void kernel_launch(void* const* d_in, const int* in_sizes, int n_in,
                              void* d_out, int out_size, void* d_ws, size_t ws_size,
                              hipStream_t stream) {
  const float* X  = (const float*)d_in[0];
  const float* Wq = (const float*)d_in[1];
  const float* Wk = (const float*)d_in[2];
  const float* Wv = (const float*)d_in[3];
  const float* Wo = (const float*)d_in[4];
  const float* bo = (const float*)d_in[5];

  unsigned short* Qb  = (unsigned short*)d_ws;   // 4M bf16 each
  unsigned short* Kb  = Qb + 4194304;
  unsigned short* Vb  = Kb + 4194304;
  unsigned short* Vst = Vb + 4194304;
  unsigned short* AO  = Vst + 4194304;
  unsigned short* Xb  = AO + 4194304;
  unsigned short* Wb  = Xb + 4194304;            // 4 x 262144
  float* LZ = (float*)(Wb + 4 * 262144);         // 65536 floats
  // total ws use: ~50.3 MB

  k_convert<<<5120, 256, 0, stream>>>(X, Wq, Wk, Wv, Wo, Xb, Wb);
  k_gemm_qkv<<<dim3(64, 8, 3), 256, 0, stream>>>(Xb, Wb, Qb);
  k_vtrans<<<dim3(32, 32), 256, 0, stream>>>(Vb, Vst);
  k_colsum<<<dim3(16, 32), 256, 0, stream>>>(Qb, Kb, LZ);
  k_attn<<<dim3(16, 32), 256, 0, stream>>>(Qb, Kb, Vst, LZ, AO);
  k_gemm_out<<<dim3(64, 8), 256, 0, stream>>>(AO, Wb + 3 * 262144, (float*)d_out, bo);
}

// Round 2
// 180.013 us; speedup vs baseline: 1.4796x; 1.4796x over previous
//
#include <hip/hip_runtime.h>

// ---------------------------------------------------------------------------
// Attention block, faithful to reference quirks:
//  - raw reshape head split: per (b,h) Q/K/V are contiguous [2048,64] slabs
//  - softmax over QUERY axis: attn[q,k] = exp(s[q,k]) / sum_q exp(s[q,k])
// Pipeline: convert | fused QKV GEMM (gll+dbuf 2-phase) | V transpose |
//           column-sum LZ | fused S/exp/PV (prefetch) | out GEMM + bias
// ---------------------------------------------------------------------------

typedef short s16v8 __attribute__((ext_vector_type(8)));
typedef float f32x4 __attribute__((ext_vector_type(4)));

#define BATCH_STRIDE 1048576   // T*D = 2048*512
#define HEAD_STRIDE  131072    // T*hd = 2048*64

__device__ __forceinline__ unsigned short f2bf(float f) {
  unsigned int u = __builtin_bit_cast(unsigned int, f);
  u = (u + 0x7FFFu + ((u >> 16) & 1u)) >> 16;   // round-to-nearest-even
  return (unsigned short)u;
}

// swizzled LDS tile: 16B chunk at slot = row*8 + (chunk ^ (row&7))
__device__ __forceinline__ s16v8 ldsfrag(const unsigned short* base, int row, int ch) {
  return *(const s16v8*)(base + (((row) << 3) + ((ch) ^ ((row) & 7))) * 8);
}

__device__ __forceinline__ f32x4 mfma16(s16v8 a, s16v8 b, f32x4 c) {
  return __builtin_amdgcn_mfma_f32_16x16x32_bf16(a, b, c, 0, 0, 0);
}

// global -> LDS direct copy, 16B per lane. lds base must be wave-uniform.
__device__ __forceinline__ void gll16(const unsigned short* g, unsigned short* l) {
  __builtin_amdgcn_global_load_lds(
      (const __attribute__((address_space(1))) void*)g,
      (__attribute__((address_space(3))) void*)l, 16, 0, 0);
}

// ---------------------------------------------------------------------------
// Kernel: f32 -> bf16 for X and the 4 weight matrices
// ---------------------------------------------------------------------------
__global__ __launch_bounds__(256) void k_convert(
    const float* __restrict__ X, const float* __restrict__ Wq,
    const float* __restrict__ Wk, const float* __restrict__ Wv,
    const float* __restrict__ Wo, unsigned short* __restrict__ Xb,
    unsigned short* __restrict__ Wb) {
  int id = blockIdx.x * 256 + threadIdx.x;  // float4 index
  const float* src;
  unsigned short* dst;
  int idx;
  if (id < 1048576) {          // X: 4,194,304 floats
    src = X; dst = Xb; idx = id;
  } else {
    int t = id - 1048576;
    int w = t >> 16;           // 65536 float4 per 512x512 weight
    idx = t & 65535;
    src = (w == 0) ? Wq : (w == 1) ? Wk : (w == 2) ? Wv : Wo;
    dst = Wb + w * 262144;
  }
  float4 v = ((const float4*)src)[idx];
  ushort4 o;
  o.x = f2bf(v.x); o.y = f2bf(v.y); o.z = f2bf(v.z); o.w = f2bf(v.w);
  ((ushort4*)dst)[idx] = o;
}

// ---------------------------------------------------------------------------
// 2-phase dbuf GEMM, BM=128 BN=128 BK=64, global_load_lds staging.
// D[i,j] = sum_d A[i,d]*W[j,d]. OUTMODE 0: bf16 out to QKV (alpha per z),
// OUTMODE 1: f32 out + bias.
// LDS slot (row,ch) holds global chunk ch^(row&7)  (pre-swizzled source).
// ---------------------------------------------------------------------------
__device__ __forceinline__ void stage_tile(
    const unsigned short* __restrict__ A, const unsigned short* __restrict__ W,
    unsigned short* lds, int m0, int n0, int k0, int wid, int lane) {
#pragma unroll
  for (int i = 0; i < 4; i++) {
    int s = wid * 4 + i;               // segment 0..15 (8 rows each)
    int row = s * 8 + (lane >> 3);
    int ch = (lane & 7) ^ (lane >> 3); // row&7 == lane>>3
    gll16(A + (size_t)(m0 + row) * 512 + k0 + ch * 8, lds + s * 512);
    gll16(W + (size_t)(n0 + row) * 512 + k0 + ch * 8, lds + 8192 + s * 512);
  }
}

template <int OUTMODE>
__device__ __forceinline__ void gemm2(
    const unsigned short* __restrict__ A, const unsigned short* __restrict__ W,
    unsigned short* __restrict__ Obf, float* __restrict__ Ofp,
    const float* __restrict__ bias, int m0, int n0) {
  __shared__ __align__(16) unsigned short SM[2][16384];  // 2 x (A 16KB | B 16KB)
  const int tid = threadIdx.x, lane = tid & 63, wid = tid >> 6;
  const int l16 = lane & 15, lg = lane >> 4;
  const int wr = wid >> 1, wc = wid & 1;   // wave tile 64x64

  const f32x4 z4 = {0.f, 0.f, 0.f, 0.f};
  f32x4 acc[4][4];
#pragma unroll
  for (int i = 0; i < 4; i++)
#pragma unroll
    for (int j = 0; j < 4; j++) acc[i][j] = z4;

  stage_tile(A, W, &SM[0][0], m0, n0, 0, wid, lane);
  __syncthreads();                         // drains vmcnt(0)
  int cur = 0;
#pragma unroll 1
  for (int t = 0; t < 8; t++) {
    if (t < 7) stage_tile(A, W, &SM[cur ^ 1][0], m0, n0, (t + 1) * 64, wid, lane);
    const unsigned short* At = &SM[cur][0];
    const unsigned short* Bt = &SM[cur][8192];
    s16v8 af[4][2], bf2[4][2];
#pragma unroll
    for (int ms = 0; ms < 4; ms++)
#pragma unroll
      for (int ks = 0; ks < 2; ks++)
        af[ms][ks] = ldsfrag(At, wr * 64 + ms * 16 + l16, ks * 4 + lg);
#pragma unroll
    for (int ns = 0; ns < 4; ns++)
#pragma unroll
      for (int ks = 0; ks < 2; ks++)
        bf2[ns][ks] = ldsfrag(Bt, wc * 64 + ns * 16 + l16, ks * 4 + lg);
#pragma unroll
    for (int ms = 0; ms < 4; ms++)
#pragma unroll
      for (int ns = 0; ns < 4; ns++)
#pragma unroll
        for (int ks = 0; ks < 2; ks++)
          acc[ms][ns] = mfma16(af[ms][ks], bf2[ns][ks], acc[ms][ns]);
    __syncthreads();                       // stage(t+1) landed; reads done
    cur ^= 1;
  }

  if (OUTMODE == 0) {
    // repack through swizzled LDS -> 16B/lane coalesced bf16 stores
    const int gc0 = n0 + wc * 64;
    const float alpha = (gc0 < 512) ? 0.125f : 1.0f;
    unsigned short* cw = &SM[0][0] + wid * 4096;   // 64x64 region per wave
#pragma unroll
    for (int ms = 0; ms < 4; ms++)
#pragma unroll
      for (int ns = 0; ns < 4; ns++)
#pragma unroll
        for (int r = 0; r < 4; r++) {
          int row = ms * 16 + lg * 4 + r;
          int col = ns * 16 + l16;
          int sw = (((col >> 3) ^ (row & 7)) << 3) + (col & 7);
          cw[row * 64 + sw] = f2bf(acc[ms][ns][r] * alpha);
        }
    __syncthreads();
    const int z = gc0 >> 9, jl = gc0 & 511;
    unsigned short* og =
        Obf + (size_t)z * 4194304 + (size_t)(m0 + wr * 64) * 512 + jl;
#pragma unroll
    for (int i = 0; i < 8; i++) {
      int row = i * 8 + (lane >> 3), ch = lane & 7;
      s16v8 v = ldsfrag(cw, row, ch);
      *(s16v8*)(og + (size_t)row * 512 + ch * 8) = v;
    }
  } else {
#pragma unroll
    for (int ms = 0; ms < 4; ms++)
#pragma unroll
      for (int ns = 0; ns < 4; ns++) {
        int gcol = n0 + wc * 64 + ns * 16 + l16;
#pragma unroll
        for (int r = 0; r < 4; r++) {
          int grow = m0 + wr * 64 + ms * 16 + lg * 4 + r;
          Ofp[(size_t)grow * 512 + gcol] = acc[ms][ns][r] + bias[gcol];
        }
      }
  }
}

__global__ __launch_bounds__(256) void k_gemm_qkv(
    const unsigned short* __restrict__ Xb, const unsigned short* __restrict__ Wb,
    unsigned short* __restrict__ QKV) {
  gemm2<0>(Xb, Wb, QKV, nullptr, nullptr, blockIdx.x * 128, blockIdx.y * 128);
}

__global__ __launch_bounds__(256) void k_gemm_out(
    const unsigned short* __restrict__ AO, const unsigned short* __restrict__ Wob,
    float* __restrict__ out, const float* __restrict__ bias) {
  gemm2<1>(AO, Wob, nullptr, out, bias, blockIdx.x * 128, blockIdx.y * 128);
}

// ---------------------------------------------------------------------------
// V transpose per (b,h): Vst[d][k] = V[k][d]
// ---------------------------------------------------------------------------
__global__ __launch_bounds__(256) void k_vtrans(
    const unsigned short* __restrict__ Vb, unsigned short* __restrict__ Vst) {
  const int kt = blockIdx.x, bh = blockIdx.y;
  const int b = bh >> 3, h = bh & 7;
  const size_t base = (size_t)b * BATCH_STRIDE + h * HEAD_STRIDE;
  const unsigned short* src = Vb + base + kt * 4096;  // [64 k][64 d]
  unsigned short* dst = Vst + base + kt * 64;         // Vst [64 d][2048 k]
  __shared__ __align__(16) unsigned short L[64][72];
  const int tid = threadIdx.x;
#pragma unroll
  for (int c = 0; c < 2; c++) {
    int cid = tid * 2 + c, row = cid >> 3, ch = cid & 7;
    *(uint4*)(&L[row][ch * 8]) = *(const uint4*)(src + row * 64 + ch * 8);
  }
  __syncthreads();
#pragma unroll
  for (int c = 0; c < 2; c++) {
    int cid = tid * 2 + c, d = cid >> 3, ch = cid & 7;
    unsigned short tmp[8];
#pragma unroll
    for (int j = 0; j < 8; j++) tmp[j] = L[ch * 8 + j][d];
    *(uint4*)(dst + (size_t)d * 2048 + ch * 8) = *(const uint4*)tmp;
  }
}

// ---------------------------------------------------------------------------
// Column softmax denominator: LZ[bh,k] = -log( sum_q exp(s[q,k]) )
// prefetched Q streaming
// ---------------------------------------------------------------------------
__global__ __launch_bounds__(256) void k_colsum(
    const unsigned short* __restrict__ Qb, const unsigned short* __restrict__ Kb,
    float* __restrict__ LZ) {
  const int kb = blockIdx.x, bh = blockIdx.y;
  const int b = bh >> 3, h = bh & 7;
  const size_t base = (size_t)b * BATCH_STRIDE + h * HEAD_STRIDE;
  const unsigned short* Qg = Qb + base;
  const unsigned short* Kg = Kb + base + kb * 8192;  // 128 rows * 64
  __shared__ __align__(16) unsigned short Kt[128 * 64];
  __shared__ __align__(16) unsigned short Qt[64 * 64];
  const int tid = threadIdx.x, lane = tid & 63, wid = tid >> 6;
  const int l16 = lane & 15, lg = lane >> 4;

#pragma unroll
  for (int c = 0; c < 4; c++) {
    int cid = tid * 4 + c, row = cid >> 3, ch = cid & 7;
    uint4 v = *(const uint4*)(Kg + row * 64 + ch * 8);
    *(uint4*)(Kt + ((row << 3) + (ch ^ (row & 7))) * 8) = v;
  }
  __syncthreads();
  s16v8 kf[2][2];
#pragma unroll
  for (int ns = 0; ns < 2; ns++)
#pragma unroll
    for (int ks = 0; ks < 2; ks++)
      kf[ns][ks] = ldsfrag(Kt, wid * 32 + ns * 16 + l16, ks * 4 + lg);

  const f32x4 z4 = {0.f, 0.f, 0.f, 0.f};
  float zsum0 = 0.f, zsum1 = 0.f;
  const int c0 = tid * 2, c1 = tid * 2 + 1;
  const int qrow0 = c0 >> 3, qch0 = c0 & 7, qrow1 = c1 >> 3, qch1 = c1 & 7;
  uint4 qr[2];
  qr[0] = *(const uint4*)(Qg + (size_t)qrow0 * 64 + qch0 * 8);
  qr[1] = *(const uint4*)(Qg + (size_t)qrow1 * 64 + qch1 * 8);
#pragma unroll 1
  for (int q0 = 0; q0 < 2048; q0 += 64) {
    __syncthreads();
    *(uint4*)(Qt + ((qrow0 << 3) + (qch0 ^ (qrow0 & 7))) * 8) = qr[0];
    *(uint4*)(Qt + ((qrow1 << 3) + (qch1 ^ (qrow1 & 7))) * 8) = qr[1];
    __syncthreads();
    if (q0 + 64 < 2048) {
      qr[0] = *(const uint4*)(Qg + (size_t)(q0 + 64 + qrow0) * 64 + qch0 * 8);
      qr[1] = *(const uint4*)(Qg + (size_t)(q0 + 64 + qrow1) * 64 + qch1 * 8);
    }
#pragma unroll
    for (int ms = 0; ms < 4; ms++) {
      s16v8 a0 = ldsfrag(Qt, ms * 16 + l16, lg);
      s16v8 a1 = ldsfrag(Qt, ms * 16 + l16, 4 + lg);
      f32x4 s0 = z4, s1 = z4;
      s0 = mfma16(a0, kf[0][0], s0);
      s0 = mfma16(a1, kf[0][1], s0);
      s1 = mfma16(a0, kf[1][0], s1);
      s1 = mfma16(a1, kf[1][1], s1);
#pragma unroll
      for (int r = 0; r < 4; r++) {
        zsum0 += __expf(s0[r]);
        zsum1 += __expf(s1[r]);
      }
    }
  }
  zsum0 += __shfl_xor(zsum0, 16); zsum0 += __shfl_xor(zsum0, 32);
  zsum1 += __shfl_xor(zsum1, 16); zsum1 += __shfl_xor(zsum1, 32);
  if (lane < 16) {
    LZ[(size_t)bh * 2048 + kb * 128 + wid * 32 + lane]      = -__logf(zsum0);
    LZ[(size_t)bh * 2048 + kb * 128 + wid * 32 + 16 + lane] = -__logf(zsum1);
  }
}

// ---------------------------------------------------------------------------
// Fused attention: AO[q,d] = sum_k exp(s[q,k]+LZ[k]) * V[k,d]
// prefetched K/V streaming
// ---------------------------------------------------------------------------
__global__ __launch_bounds__(256) void k_attn(
    const unsigned short* __restrict__ Qb, const unsigned short* __restrict__ Kb,
    const unsigned short* __restrict__ Vst, const float* __restrict__ LZ,
    unsigned short* __restrict__ AO) {
  const int qb = blockIdx.x, bh = blockIdx.y;
  const int b = bh >> 3, h = bh & 7;
  const size_t base = (size_t)b * BATCH_STRIDE + h * HEAD_STRIDE;
  const unsigned short* Qg = Qb + base + qb * 8192;
  const unsigned short* Kg = Kb + base;
  const unsigned short* Vg = Vst + base;
  const float* lzg = LZ + (size_t)bh * 2048;
  unsigned short* aog = AO + base + qb * 8192;

  __shared__ __align__(16) unsigned short Qt[128 * 64];
  __shared__ __align__(16) unsigned short Kt[64 * 64];
  __shared__ __align__(16) unsigned short Vt[64 * 64];
  __shared__ __align__(16) float Pw[4][32 * 36];
  __shared__ float lzs[64];

  const int tid = threadIdx.x, lane = tid & 63, wid = tid >> 6;
  const int l16 = lane & 15, lg = lane >> 4;

#pragma unroll
  for (int c = 0; c < 4; c++) {
    int cid = tid * 4 + c, row = cid >> 3, ch = cid & 7;
    uint4 v = *(const uint4*)(Qg + row * 64 + ch * 8);
    *(uint4*)(Qt + ((row << 3) + (ch ^ (row & 7))) * 8) = v;
  }
  __syncthreads();
  s16v8 qa[2][2];
#pragma unroll
  for (int ms = 0; ms < 2; ms++)
#pragma unroll
    for (int ks = 0; ks < 2; ks++)
      qa[ms][ks] = ldsfrag(Qt, wid * 32 + ms * 16 + l16, ks * 4 + lg);

  const f32x4 z4 = {0.f, 0.f, 0.f, 0.f};
  f32x4 oacc[2][4];
#pragma unroll
  for (int ms = 0; ms < 2; ms++)
#pragma unroll
    for (int dt = 0; dt < 4; dt++) oacc[ms][dt] = z4;

  const int c0 = tid * 2, c1 = tid * 2 + 1;
  const int r0 = c0 >> 3, ch0 = c0 & 7, r1 = c1 >> 3, ch1 = c1 & 7;
  uint4 kr[2], vr[2];
  float lzv = 0.f;
  kr[0] = *(const uint4*)(Kg + (size_t)r0 * 64 + ch0 * 8);
  kr[1] = *(const uint4*)(Kg + (size_t)r1 * 64 + ch1 * 8);
  vr[0] = *(const uint4*)(Vg + (size_t)r0 * 2048 + ch0 * 8);
  vr[1] = *(const uint4*)(Vg + (size_t)r1 * 2048 + ch1 * 8);
  if (tid < 64) lzv = lzg[tid];

#pragma unroll 1
  for (int k0 = 0; k0 < 2048; k0 += 64) {
    __syncthreads();
    *(uint4*)(Kt + ((r0 << 3) + (ch0 ^ (r0 & 7))) * 8) = kr[0];
    *(uint4*)(Kt + ((r1 << 3) + (ch1 ^ (r1 & 7))) * 8) = kr[1];
    *(uint4*)(Vt + ((r0 << 3) + (ch0 ^ (r0 & 7))) * 8) = vr[0];
    *(uint4*)(Vt + ((r1 << 3) + (ch1 ^ (r1 & 7))) * 8) = vr[1];
    if (tid < 64) lzs[tid] = lzv;
    __syncthreads();
    if (k0 + 64 < 2048) {
      int kn = k0 + 64;
      kr[0] = *(const uint4*)(Kg + (size_t)(kn + r0) * 64 + ch0 * 8);
      kr[1] = *(const uint4*)(Kg + (size_t)(kn + r1) * 64 + ch1 * 8);
      vr[0] = *(const uint4*)(Vg + (size_t)r0 * 2048 + kn + ch0 * 8);
      vr[1] = *(const uint4*)(Vg + (size_t)r1 * 2048 + kn + ch1 * 8);
      if (tid < 64) lzv = lzg[kn + tid];
    }

    f32x4 sacc[2][4];
#pragma unroll
    for (int ms = 0; ms < 2; ms++)
#pragma unroll
      for (int kc = 0; kc < 4; kc++) sacc[ms][kc] = z4;
#pragma unroll
    for (int kc = 0; kc < 4; kc++)
#pragma unroll
      for (int ks = 0; ks < 2; ks++) {
        s16v8 kfr = ldsfrag(Kt, kc * 16 + l16, ks * 4 + lg);
        sacc[0][kc] = mfma16(qa[0][ks], kfr, sacc[0][kc]);
        sacc[1][kc] = mfma16(qa[1][ks], kfr, sacc[1][kc]);
      }

#pragma unroll
    for (int half = 0; half < 2; half++) {
#pragma unroll
      for (int kc2 = 0; kc2 < 2; kc2++) {
        int kc = half * 2 + kc2;
        float lz = lzs[kc * 16 + l16];
#pragma unroll
        for (int ms = 0; ms < 2; ms++)
#pragma unroll
          for (int r = 0; r < 4; r++) {
            float p = __expf(sacc[ms][kc][r] + lz);
            Pw[wid][(ms * 16 + lg * 4 + r) * 36 + kc2 * 16 + l16] = p;
          }
      }
      s16v8 pa[2];
#pragma unroll
      for (int ms = 0; ms < 2; ms++) {
        const float* p = &Pw[wid][(ms * 16 + l16) * 36 + lg * 8];
        s16v8 t;
#pragma unroll
        for (int j = 0; j < 8; j++) t[j] = (short)f2bf(p[j]);
        pa[ms] = t;
      }
#pragma unroll
      for (int dt = 0; dt < 4; dt++) {
        s16v8 vb = ldsfrag(Vt, dt * 16 + l16, half * 4 + lg);
        oacc[0][dt] = mfma16(pa[0], vb, oacc[0][dt]);
        oacc[1][dt] = mfma16(pa[1], vb, oacc[1][dt]);
      }
    }
  }
#pragma unroll
  for (int ms = 0; ms < 2; ms++)
#pragma unroll
    for (int dt = 0; dt < 4; dt++)
#pragma unroll
      for (int r = 0; r < 4; r++) {
        int row = wid * 32 + ms * 16 + lg * 4 + r;
        aog[row * 64 + dt * 16 + l16] = f2bf(oacc[ms][dt][r]);
      }
}

// ---------------------------------------------------------------------------
extern "C" void kernel_launch(void* const* d_in, const int* in_sizes, int n_in,
                              void* d_out, int out_size, void* d_ws, size_t ws_size,
                              hipStream_t stream) {
  const float* X  = (const float*)d_in[0];
  const float* Wq = (const float*)d_in[1];
  const float* Wk = (const float*)d_in[2];
  const float* Wv = (const float*)d_in[3];
  const float* Wo = (const float*)d_in[4];
  const float* bo = (const float*)d_in[5];

  unsigned short* Qb  = (unsigned short*)d_ws;   // QKV contiguous: 3 x 4M bf16
  unsigned short* Kb  = Qb + 4194304;
  unsigned short* Vb  = Kb + 4194304;
  unsigned short* Vst = Vb + 4194304;
  unsigned short* AO  = Vst + 4194304;
  unsigned short* Xb  = AO + 4194304;
  unsigned short* Wb  = Xb + 4194304;            // 4 x 262144 (Wq,Wk,Wv,Wo)
  float* LZ = (float*)(Wb + 4 * 262144);         // 65536 floats

  k_convert<<<5120, 256, 0, stream>>>(X, Wq, Wk, Wv, Wo, Xb, Wb);
  k_gemm_qkv<<<dim3(64, 12), 256, 0, stream>>>(Xb, Wb, Qb);
  k_vtrans<<<dim3(32, 32), 256, 0, stream>>>(Vb, Vst);
  k_colsum<<<dim3(16, 32), 256, 0, stream>>>(Qb, Kb, LZ);
  k_attn<<<dim3(16, 32), 256, 0, stream>>>(Qb, Kb, Vst, LZ, AO);
  k_gemm_out<<<dim3(64, 4), 256, 0, stream>>>(AO, Wb + 3 * 262144, (float*)d_out, bo);
}

// Round 5
// 149.752 us; speedup vs baseline: 1.7786x; 1.2021x over previous
//
#include <hip/hip_runtime.h>

// ---------------------------------------------------------------------------
// Attention block, faithful to reference quirks:
//  - raw reshape head split: per (b,h) Q/K/V are contiguous [2048,64] slabs
//  - softmax over QUERY axis: attn[q,k] = exp(s[q,k]) / sum_q exp(s[q,k])
// Algebra: Z[k] = sum_q exp(s); fold 1/Z into V (Vn = V/Z); out = exp(S)@Vn.
// Pipeline: convert | fused QKV GEMM | colv (Z + V-scale + V-transpose) |
//           attn (swapped-QK register-P flash) | out GEMM + bias
// ---------------------------------------------------------------------------

typedef unsigned short ush;
typedef short s16v8 __attribute__((ext_vector_type(8)));
typedef float f32x4 __attribute__((ext_vector_type(4)));

#define BATCH_STRIDE 1048576   // T*D = 2048*512
#define HEAD_STRIDE  131072    // T*hd = 2048*64

__device__ __forceinline__ ush f2bf(float f) {
  unsigned int u = __builtin_bit_cast(unsigned int, f);
  u = (u + 0x7FFFu + ((u >> 16) & 1u)) >> 16;   // round-to-nearest-even
  return (ush)u;
}
__device__ __forceinline__ float bf2f(ush u) {
  return __builtin_bit_cast(float, (unsigned int)u << 16);
}
// fast pack two f32 -> 2xbf16 u32 (round-half-up; P is positive & well-scaled)
__device__ __forceinline__ unsigned int bfpack(float lo, float hi) {
  unsigned int ul = __builtin_bit_cast(unsigned int, lo) + 0x8000u;
  unsigned int uh = __builtin_bit_cast(unsigned int, hi) + 0x8000u;
  return (uh & 0xFFFF0000u) | (ul >> 16);
}

// swizzled LDS tile (8-chunk rows): 16B chunk at slot = row*8 + (ch ^ (row&7))
__device__ __forceinline__ s16v8 ldsfrag(const ush* base, int row, int ch) {
  return *(const s16v8*)(base + (((row) << 3) + ((ch) ^ ((row) & 7))) * 8);
}

__device__ __forceinline__ f32x4 mfma16(s16v8 a, s16v8 b, f32x4 c) {
  return __builtin_amdgcn_mfma_f32_16x16x32_bf16(a, b, c, 0, 0, 0);
}

__device__ __forceinline__ void gll16(const ush* g, ush* l) {
  __builtin_amdgcn_global_load_lds(
      (const __attribute__((address_space(1))) void*)g,
      (__attribute__((address_space(3))) void*)l, 16, 0, 0);
}

// ---------------------------------------------------------------------------
// f32 -> bf16 for X and the 4 weight matrices
// ---------------------------------------------------------------------------
__global__ __launch_bounds__(256) void k_convert(
    const float* __restrict__ X, const float* __restrict__ Wq,
    const float* __restrict__ Wk, const float* __restrict__ Wv,
    const float* __restrict__ Wo, ush* __restrict__ Xb, ush* __restrict__ Wb) {
  int id = blockIdx.x * 256 + threadIdx.x;
  const float* src;
  ush* dst;
  int idx;
  if (id < 1048576) {
    src = X; dst = Xb; idx = id;
  } else {
    int t = id - 1048576;
    int w = t >> 16;
    idx = t & 65535;
    src = (w == 0) ? Wq : (w == 1) ? Wk : (w == 2) ? Wv : Wo;
    dst = Wb + w * 262144;
  }
  float4 v = ((const float4*)src)[idx];
  ushort4 o;
  o.x = f2bf(v.x); o.y = f2bf(v.y); o.z = f2bf(v.z); o.w = f2bf(v.w);
  ((ushort4*)dst)[idx] = o;
}

// ---------------------------------------------------------------------------
// 2-phase dbuf GEMM, BM=128 BN=128 BK=64 (verified round 2)
// ---------------------------------------------------------------------------
__device__ __forceinline__ void stage_tile(
    const ush* __restrict__ A, const ush* __restrict__ W,
    ush* lds, int m0, int n0, int k0, int wid, int lane) {
#pragma unroll
  for (int i = 0; i < 4; i++) {
    int s = wid * 4 + i;
    int row = s * 8 + (lane >> 3);
    int ch = (lane & 7) ^ (lane >> 3);
    gll16(A + (size_t)(m0 + row) * 512 + k0 + ch * 8, lds + s * 512);
    gll16(W + (size_t)(n0 + row) * 512 + k0 + ch * 8, lds + 8192 + s * 512);
  }
}

template <int OUTMODE>
__device__ __forceinline__ void gemm2(
    const ush* __restrict__ A, const ush* __restrict__ W,
    ush* __restrict__ Obf, float* __restrict__ Ofp,
    const float* __restrict__ bias, int m0, int n0) {
  __shared__ __align__(16) ush SM[2][16384];
  const int tid = threadIdx.x, lane = tid & 63, wid = tid >> 6;
  const int l16 = lane & 15, lg = lane >> 4;
  const int wr = wid >> 1, wc = wid & 1;

  const f32x4 z4 = {0.f, 0.f, 0.f, 0.f};
  f32x4 acc[4][4];
#pragma unroll
  for (int i = 0; i < 4; i++)
#pragma unroll
    for (int j = 0; j < 4; j++) acc[i][j] = z4;

  stage_tile(A, W, &SM[0][0], m0, n0, 0, wid, lane);
  __syncthreads();
  int cur = 0;
#pragma unroll 1
  for (int t = 0; t < 8; t++) {
    if (t < 7) stage_tile(A, W, &SM[cur ^ 1][0], m0, n0, (t + 1) * 64, wid, lane);
    const ush* At = &SM[cur][0];
    const ush* Bt = &SM[cur][8192];
    s16v8 af[4][2], bf2[4][2];
#pragma unroll
    for (int ms = 0; ms < 4; ms++)
#pragma unroll
      for (int ks = 0; ks < 2; ks++)
        af[ms][ks] = ldsfrag(At, wr * 64 + ms * 16 + l16, ks * 4 + lg);
#pragma unroll
    for (int ns = 0; ns < 4; ns++)
#pragma unroll
      for (int ks = 0; ks < 2; ks++)
        bf2[ns][ks] = ldsfrag(Bt, wc * 64 + ns * 16 + l16, ks * 4 + lg);
#pragma unroll
    for (int ms = 0; ms < 4; ms++)
#pragma unroll
      for (int ns = 0; ns < 4; ns++)
#pragma unroll
        for (int ks = 0; ks < 2; ks++)
          acc[ms][ns] = mfma16(af[ms][ks], bf2[ns][ks], acc[ms][ns]);
    __syncthreads();
    cur ^= 1;
  }

  if (OUTMODE == 0) {
    const int gc0 = n0 + wc * 64;
    const float alpha = (gc0 < 512) ? 0.125f : 1.0f;
    ush* cw = &SM[0][0] + wid * 4096;
#pragma unroll
    for (int ms = 0; ms < 4; ms++)
#pragma unroll
      for (int ns = 0; ns < 4; ns++)
#pragma unroll
        for (int r = 0; r < 4; r++) {
          int row = ms * 16 + lg * 4 + r;
          int col = ns * 16 + l16;
          int sw = (((col >> 3) ^ (row & 7)) << 3) + (col & 7);
          cw[row * 64 + sw] = f2bf(acc[ms][ns][r] * alpha);
        }
    __syncthreads();
    const int z = gc0 >> 9, jl = gc0 & 511;
    ush* og = Obf + (size_t)z * 4194304 + (size_t)(m0 + wr * 64) * 512 + jl;
#pragma unroll
    for (int i = 0; i < 8; i++) {
      int row = i * 8 + (lane >> 3), ch = lane & 7;
      s16v8 v = ldsfrag(cw, row, ch);
      *(s16v8*)(og + (size_t)row * 512 + ch * 8) = v;
    }
  } else {
#pragma unroll
    for (int ms = 0; ms < 4; ms++)
#pragma unroll
      for (int ns = 0; ns < 4; ns++) {
        int gcol = n0 + wc * 64 + ns * 16 + l16;
#pragma unroll
        for (int r = 0; r < 4; r++) {
          int grow = m0 + wr * 64 + ms * 16 + lg * 4 + r;
          Ofp[(size_t)grow * 512 + gcol] = acc[ms][ns][r] + bias[gcol];
        }
      }
  }
}

__global__ __launch_bounds__(256) void k_gemm_qkv(
    const ush* __restrict__ Xb, const ush* __restrict__ Wb,
    ush* __restrict__ QKV) {
  gemm2<0>(Xb, Wb, QKV, nullptr, nullptr, blockIdx.x * 128, blockIdx.y * 128);
}

__global__ __launch_bounds__(256) void k_gemm_out(
    const ush* __restrict__ AO, const ush* __restrict__ Wob,
    float* __restrict__ out, const float* __restrict__ bias) {
  gemm2<1>(AO, Wob, nullptr, out, bias, blockIdx.x * 128, blockIdx.y * 128);
}

// ---------------------------------------------------------------------------
// k_colv: per (kt: 64 k-rows, bh): Z[k] = sum_q exp(s[q,k]) via swapped-QK
// (K rows as A-operand, held in regs; Q direct-global), then Vn = V/Z
// written transposed: Vst[d][2048 k].
// ---------------------------------------------------------------------------
__global__ __launch_bounds__(256) void k_colv(
    const ush* __restrict__ Qb, const ush* __restrict__ Kb,
    const ush* __restrict__ Vb, ush* __restrict__ Vst) {
  const int wg = blockIdx.x;
  const int xcd = wg & 7, slot = wg >> 3;
  const int bh = xcd * 4 + (slot >> 5), kt = slot & 31;
  const int b = bh >> 3, h = bh & 7;
  const size_t base = (size_t)b * BATCH_STRIDE + h * HEAD_STRIDE;
  const ush* Qg = Qb + base;
  const ush* Kg = Kb + base + kt * 4096;
  const ush* Vg = Vb + base + kt * 4096;
  ush* dst = Vst + base + kt * 64;

  __shared__ float Zp[256];
  __shared__ float invZ[64];
  __shared__ __align__(16) ush L[64][72];

  const int tid = threadIdx.x, lane = tid & 63, wid = tid >> 6;
  const int l16 = lane & 15, lg = lane >> 4;

  // V tile loaded early (latency hidden under the Z pass)
  const int cid0 = tid * 2, cid1 = tid * 2 + 1;
  uint4 vr0 = *(const uint4*)(Vg + (size_t)(cid0 >> 3) * 64 + (cid0 & 7) * 8);
  uint4 vr1 = *(const uint4*)(Vg + (size_t)(cid1 >> 3) * 64 + (cid1 & 7) * 8);

  // K fragments (A-operand): rows kc*16+l16, hd = ks*32 + lg*8..+7
  s16v8 kf[4][2];
#pragma unroll
  for (int kc = 0; kc < 4; kc++)
#pragma unroll
    for (int ks = 0; ks < 2; ks++)
      kf[kc][ks] = *(const s16v8*)(Kg + (size_t)(kc * 16 + l16) * 64 + ks * 32 + lg * 8);

  const f32x4 z4 = {0.f, 0.f, 0.f, 0.f};
  f32x4 zacc[4];
#pragma unroll
  for (int kc = 0; kc < 4; kc++) zacc[kc] = z4;

#pragma unroll 1
  for (int t = 0; t < 8; t++) {
    size_t q0 = (size_t)(t * 4 + wid) * 64;
#pragma unroll
    for (int ms = 0; ms < 4; ms++) {
      const ush* qrow = Qg + (q0 + ms * 16 + l16) * 64;
      s16v8 qf0 = *(const s16v8*)(qrow + lg * 8);
      s16v8 qf1 = *(const s16v8*)(qrow + 32 + lg * 8);
#pragma unroll
      for (int kc = 0; kc < 4; kc++) {
        f32x4 s = mfma16(kf[kc][0], qf0, z4);
        s = mfma16(kf[kc][1], qf1, s);
#pragma unroll
        for (int r = 0; r < 4; r++) zacc[kc][r] += __expf(s[r]);
      }
    }
  }

  // write V tile to LDS (plain, padded) while reducing Z
  *(uint4*)(&L[cid0 >> 3][(cid0 & 7) * 8]) = vr0;
  *(uint4*)(&L[cid1 >> 3][(cid1 & 7) * 8]) = vr1;

#pragma unroll
  for (int kc = 0; kc < 4; kc++)
#pragma unroll
    for (int r = 0; r < 4; r++) {
      float v = zacc[kc][r];
      v += __shfl_xor(v, 1); v += __shfl_xor(v, 2);
      v += __shfl_xor(v, 4); v += __shfl_xor(v, 8);
      if (l16 == 0) Zp[wid * 64 + kc * 16 + lg * 4 + r] = v;
    }
  __syncthreads();
  if (tid < 64)
    invZ[tid] = 1.0f / (Zp[tid] + Zp[64 + tid] + Zp[128 + tid] + Zp[192 + tid]);
  __syncthreads();

  // transpose + scale: Vn^T[d][k]
#pragma unroll
  for (int c = 0; c < 2; c++) {
    int cid = tid * 2 + c, d = cid >> 3, ch = cid & 7;
    float4 iz0 = *(const float4*)(invZ + ch * 8);
    float4 iz1 = *(const float4*)(invZ + ch * 8 + 4);
    ush tmp[8];
#pragma unroll
    for (int j = 0; j < 4; j++) tmp[j] = f2bf(bf2f(L[ch * 8 + j][d]) * iz0[j]);
#pragma unroll
    for (int j = 0; j < 4; j++) tmp[4 + j] = f2bf(bf2f(L[ch * 8 + 4 + j][d]) * iz1[j]);
    *(uint4*)(dst + (size_t)d * 2048 + ch * 8) = *(const uint4*)tmp;
  }
}

// ---------------------------------------------------------------------------
// k_attn: out[q,d] = sum_k exp(s[q,k]) * Vn[k,d]
// Block: 64 q rows (qb*4096 elems); 4 waves each own a 16-k slice per tile.
// Swapped QK (A=K) => lane holds P[q=l16][k=lg*4+r]: exact A-frag layout.
// Two 64-k tiles paired per iteration to fill K=32 MFMA fragments.
// ---------------------------------------------------------------------------
__global__ __launch_bounds__(256) void k_attn(
    const ush* __restrict__ Qb, const ush* __restrict__ Kb,
    const ush* __restrict__ Vst, ush* __restrict__ AO) {
  const int wg = blockIdx.x;
  const int xcd = wg & 7, slot = wg >> 3;
  const int bh = xcd * 4 + (slot >> 5), qb = slot & 31;
  const int b = bh >> 3, h = bh & 7;
  const size_t base = (size_t)b * BATCH_STRIDE + h * HEAD_STRIDE;
  const ush* Qg = Qb + base + qb * 4096;   // 64 q rows x 64 dims
  const ush* Kg = Kb + base;
  const ush* Vg = Vst + base;              // [64 d][2048 k]
  ush* aog = AO + base + qb * 4096;

  __shared__ __align__(16) char smraw[34816];   // 2x16KB V dbuf; epilogue alias

  const int tid = threadIdx.x, lane = tid & 63, wid = tid >> 6;
  const int l16 = lane & 15, lg = lane >> 4;

  // Q fragments direct from global (held whole kernel)
  s16v8 qa[4][2];
#pragma unroll
  for (int ms = 0; ms < 4; ms++)
#pragma unroll
    for (int ks = 0; ks < 2; ks++)
      qa[ms][ks] = *(const s16v8*)(Qg + (size_t)(ms * 16 + l16) * 64 + ks * 32 + lg * 8);

  const f32x4 z4 = {0.f, 0.f, 0.f, 0.f};
  f32x4 oacc[4][4];
#pragma unroll
  for (int i = 0; i < 4; i++)
#pragma unroll
    for (int j = 0; j < 4; j++) oacc[i][j] = z4;

  // stage 128-k V super-tile: [64 d][16 chunks], chunk slot = c ^ (row&7)
  auto stage_v = [&](ush* buf, size_t k0g) {
#pragma unroll
    for (int rd = 0; rd < 4; rd++) {
      int idb = rd * 256 + wid * 64;
      int id = idb + lane;
      int row = id >> 4, sc = id & 15;
      int srcc = (sc & 7) ^ (row & 7);
      gll16(Vg + (size_t)row * 2048 + k0g + ((sc & 8) | srcc) * 8, buf + idb * 8);
    }
  };

  stage_v((ush*)smraw, 0);
  __syncthreads();
  int cur = 0;

  const size_t kwoff = (size_t)(16 * wid + l16) * 64;
#pragma unroll 1
  for (int tp = 0; tp < 16; tp++) {
    if (tp < 15) stage_v((ush*)smraw + (cur ^ 1) * 8192, (size_t)(tp + 1) * 128);
    const ush* Vt = (const ush*)smraw + cur * 8192;

    // K fragments for both tiles of the pair (direct global)
    const ush* kr = Kg + (size_t)tp * 128 * 64 + kwoff;
    s16v8 kf0[2], kf1[2];
    kf0[0] = *(const s16v8*)(kr + lg * 8);
    kf0[1] = *(const s16v8*)(kr + 32 + lg * 8);
    kf1[0] = *(const s16v8*)(kr + 4096 + lg * 8);
    kf1[1] = *(const s16v8*)(kr + 4096 + 32 + lg * 8);

    // Vn B-fragments: per dt, 4 bf16 from each tile half
    uint4 vbu[4];
#pragma unroll
    for (int dt = 0; dt < 4; dt++) {
      int row = dt * 16 + l16;
      int cA = 2 * wid + (lg >> 1);
      int offA = row * 128 + (cA ^ (row & 7)) * 8 + (lg & 1) * 4;
      uint2 a = *(const uint2*)(Vt + offA);
      uint2 bq = *(const uint2*)(Vt + offA + 64);
      vbu[dt].x = a.x; vbu[dt].y = a.y; vbu[dt].z = bq.x; vbu[dt].w = bq.y;
    }

#pragma unroll
    for (int ms = 0; ms < 4; ms++) {
      f32x4 sA = mfma16(kf0[0], qa[ms][0], z4);
      sA = mfma16(kf0[1], qa[ms][1], sA);
      f32x4 sB = mfma16(kf1[0], qa[ms][0], z4);
      sB = mfma16(kf1[1], qa[ms][1], sB);
      uint4 pu;
      pu.x = bfpack(__expf(sA[0]), __expf(sA[1]));
      pu.y = bfpack(__expf(sA[2]), __expf(sA[3]));
      pu.z = bfpack(__expf(sB[0]), __expf(sB[1]));
      pu.w = bfpack(__expf(sB[2]), __expf(sB[3]));
      s16v8 pa = __builtin_bit_cast(s16v8, pu);
#pragma unroll
      for (int dt = 0; dt < 4; dt++)
        oacc[ms][dt] = mfma16(pa, __builtin_bit_cast(s16v8, vbu[dt]), oacc[ms][dt]);
    }
    __syncthreads();
    cur ^= 1;
  }

  // ---- cross-wave k-slice reduction ----
  float* red = (float*)smraw;
  float* r0 = red;
  float* r1 = red + 64 * 68;
  if (wid >= 2) {
    float* rg = (wid == 2) ? r0 : r1;
#pragma unroll
    for (int ms = 0; ms < 4; ms++)
#pragma unroll
      for (int dt = 0; dt < 4; dt++)
        *(f32x4*)(rg + lane * 68 + (ms * 4 + dt) * 4) = oacc[ms][dt];
  }
  __syncthreads();
  if (wid < 2) {
    float* rg = (wid == 0) ? r0 : r1;
#pragma unroll
    for (int ms = 0; ms < 4; ms++)
#pragma unroll
      for (int dt = 0; dt < 4; dt++)
        oacc[ms][dt] += *(const f32x4*)(rg + lane * 68 + (ms * 4 + dt) * 4);
  }
  __syncthreads();
  if (wid == 1) {
#pragma unroll
    for (int ms = 0; ms < 4; ms++)
#pragma unroll
      for (int dt = 0; dt < 4; dt++)
        *(f32x4*)(r0 + lane * 68 + (ms * 4 + dt) * 4) = oacc[ms][dt];
  }
  __syncthreads();
  if (wid == 0) {
#pragma unroll
    for (int ms = 0; ms < 4; ms++)
#pragma unroll
      for (int dt = 0; dt < 4; dt++)
        oacc[ms][dt] += *(const f32x4*)(r0 + lane * 68 + (ms * 4 + dt) * 4);
  }
  __syncthreads();   // all reads of r0 done before out-tile overwrites it
  ush* ot = (ush*)smraw;   // 64x64 bf16 out tile (aliases r0)
  if (wid == 0) {
#pragma unroll
    for (int ms = 0; ms < 4; ms++)
#pragma unroll
      for (int dt = 0; dt < 4; dt++)
#pragma unroll
        for (int r = 0; r < 4; r++)
          ot[(ms * 16 + lg * 4 + r) * 64 + dt * 16 + l16] = f2bf(oacc[ms][dt][r]);
  }
  __syncthreads();
#pragma unroll
  for (int rd = 0; rd < 2; rd++) {
    int id = rd * 256 + tid;
    *(s16v8*)(aog + id * 8) = *(const s16v8*)(ot + id * 8);
  }
}

// ---------------------------------------------------------------------------
extern "C" void kernel_launch(void* const* d_in, const int* in_sizes, int n_in,
                              void* d_out, int out_size, void* d_ws, size_t ws_size,
                              hipStream_t stream) {
  const float* X  = (const float*)d_in[0];
  const float* Wq = (const float*)d_in[1];
  const float* Wk = (const float*)d_in[2];
  const float* Wv = (const float*)d_in[3];
  const float* Wo = (const float*)d_in[4];
  const float* bo = (const float*)d_in[5];

  ush* Qb  = (ush*)d_ws;          // QKV contiguous: 3 x 4M bf16
  ush* Kb  = Qb + 4194304;
  ush* Vb  = Kb + 4194304;
  ush* Vst = Vb + 4194304;        // Vn transposed [d][k] per head
  ush* AO  = Vst + 4194304;
  ush* Xb  = AO + 4194304;
  ush* Wb  = Xb + 4194304;        // 4 x 262144 (Wq,Wk,Wv,Wo)

  k_convert<<<5120, 256, 0, stream>>>(X, Wq, Wk, Wv, Wo, Xb, Wb);
  k_gemm_qkv<<<dim3(64, 12), 256, 0, stream>>>(Xb, Wb, Qb);
  k_colv<<<1024, 256, 0, stream>>>(Qb, Kb, Vb, Vst);
  k_attn<<<1024, 256, 0, stream>>>(Qb, Kb, Vst, AO);
  k_gemm_out<<<dim3(64, 4), 256, 0, stream>>>(AO, Wb + 3 * 262144, (float*)d_out, bo);
}